// Round 14
// baseline (333.262 us; speedup 1.0000x reference)
//
#include <hip/hip_runtime.h>
#include <hip/hip_bf16.h>

// CrissCross attention, B=8 C=256 H=W=96 CQ=32. Flash-style split softmax, fp16.
// 6 dispatches total (pairs merged via blockIdx.z everywhere):
//  pack_all : [wq|wk|wv] -> f16 Wall[320][256] + fp32 ball[320], both inputs
//  proj_all : 512-thr 8-wave f16-MFMA blocks; K-quarter pipelined staging
//             (R13), swizzled LDS (R11), __launch_bounds__(512,2) so the
//             compiler has a 256-reg budget for deep load pipelining (R13
//             post-mortem: 128-reg cap serialized the fragment loads), and
//             Pt epilogue routed through LDS for full-line stores (kills the
//             26MB write amplification) -> Pt[b][n][64] + vW[b][h][c][w]
//  vtrans   : vW* -> vH*[b][w][c][g]
//  attn     : z&1: 0 = (b,h) e_w pass, 1 = (b,w) e_h pass (diag mask); z>>1 = pair.
//             LDS-staged q/k, MFMA QK^T, in-reg wave softmax, staged V halves,
//             PV MFMA, LDS-transposed coalesced stores.
//  scl      : exact concat-softmax rescale (gamma folded), both pairs
//  tkomb    : out = x + tmpH^T*sclH + tmpW*sclW (transpose fused), both pairs

#define Bn 8
#define Cn 256
#define NHW 9216
#define PT_BS ((size_t)NHW * 64)

typedef unsigned short u16;
typedef __attribute__((ext_vector_type(8))) _Float16 f16x8;
typedef __attribute__((ext_vector_type(4))) float f32x4;

__device__ __forceinline__ float h2f(u16 v) {
  _Float16 h;
  __builtin_memcpy(&h, &v, 2);
  return (float)h;
}
__device__ __forceinline__ u16 f2h(float f) {
  _Float16 h = (_Float16)f;
  u16 v;
  __builtin_memcpy(&v, &h, 2);
  return v;
}

__global__ __launch_bounds__(256) void pack_all(const float* __restrict__ wq0, const float* __restrict__ bq0,
                                                const float* __restrict__ wk0, const float* __restrict__ bk0,
                                                const float* __restrict__ wv0, const float* __restrict__ bv0,
                                                const float* __restrict__ wq1, const float* __restrict__ bq1,
                                                const float* __restrict__ wk1, const float* __restrict__ bk1,
                                                const float* __restrict__ wv1, const float* __restrict__ bv1,
                                                u16* __restrict__ Wall0, float* __restrict__ ball0,
                                                u16* __restrict__ Wall1, float* __restrict__ ball1) {
  const int pr = blockIdx.y;
  const float* wq = pr ? wq1 : wq0;
  const float* bq = pr ? bq1 : bq0;
  const float* wk = pr ? wk1 : wk0;
  const float* bk = pr ? bk1 : bk0;
  const float* wv = pr ? wv1 : wv0;
  const float* bv = pr ? bv1 : bv0;
  u16* Wall = pr ? Wall1 : Wall0;
  float* ball = pr ? ball1 : ball0;
  int i = blockIdx.x * 256 + threadIdx.x;
  if (i < 320 * 256) {
    int o = i >> 8, c = i & 255;
    float v = (o < 32) ? wq[o * 256 + c] : (o < 64) ? wk[(o - 32) * 256 + c] : wv[(o - 64) * 256 + c];
    Wall[i] = f2h(v);
  }
  if (i < 320) ball[i] = (i < 32) ? bq[i] : (i < 64) ? bk[i - 32] : bv[i - 64];
}

// Fused projection: block (h, b, pair). 512 threads = 8 waves (mg = wv>>1, ng = wv&1).
// Wave (mg,ng): m-tiles {mg+4j, j=0..4} (j=0 -> qk tile), n-tiles ng*48 + {0,16,32}.
// xs element (row n, col k) lives at xs[row*264 + (col ^ (((row>>2)&7)<<3))].
__global__ __launch_bounds__(512, 2) void proj_all(const float* __restrict__ X0, const float* __restrict__ X1,
                                                   const u16* __restrict__ Wall0, const u16* __restrict__ Wall1,
                                                   const float* __restrict__ ball0, const float* __restrict__ ball1,
                                                   u16* __restrict__ Pt0, u16* __restrict__ Pt1,
                                                   u16* __restrict__ vW0, u16* __restrict__ vW1) {
  __shared__ __align__(16) u16 xs[96 * 264];  // 50688 B, swizzled [n][cin]
  u16* sO = xs;                               // overlay: [96][72] qk / [128][104] v
  const int h = blockIdx.x, b = blockIdx.y, pr = blockIdx.z;
  const float* X = pr ? X1 : X0;
  const u16* Wall = pr ? Wall1 : Wall0;
  const float* ball = pr ? ball1 : ball0;
  u16* Pt = pr ? Pt1 : Pt0;
  u16* vW = pr ? vW1 : vW0;
  const int tid = threadIdx.x;
  const float* Xb = X + (size_t)b * Cn * NHW + h * 96;
  // staging task (per quarter): 384 tasks = 16 tcq (4-cin quads) x 24 tn4 (4-n quads)
  const int tcq = tid / 24, tn4 = tid % 24;
  const bool act = tid < 384;
  const int lane = tid & 63, wv = tid >> 6;  // wv 0..7
  const int mg = wv >> 1, ng = wv & 1;
  const int arow = lane & 15;
  const int g = lane >> 4;
  const int kc = g * 8;
  const u16* wrow[5];
#pragma unroll
  for (int j = 0; j < 5; ++j)
    wrow[j] = Wall + (size_t)((mg + 4 * j) * 16 + arow) * 256 + kc;
  int rbase[3], rsw[3];
#pragma unroll
  for (int nt = 0; nt < 3; ++nt) {
    int row = ng * 48 + nt * 16 + arow;
    rbase[nt] = row * 264;
    rsw[nt] = ((row >> 2) & 7) << 3;
  }
  float4 pre[4];
  // prologue: load + write quarter 0
  if (act) {
    const float* src = Xb + (size_t)(4 * tcq) * NHW + tn4 * 4;
#pragma unroll
    for (int j = 0; j < 4; ++j) pre[j] = *(const float4*)(src + (size_t)j * NHW);
    int colb = (4 * tcq) ^ ((tn4 & 7) << 3);
#pragma unroll
    for (int i = 0; i < 4; ++i) {
      ushort4 wv4;
      wv4.x = f2h(((const float*)&pre[0])[i]);
      wv4.y = f2h(((const float*)&pre[1])[i]);
      wv4.z = f2h(((const float*)&pre[2])[i]);
      wv4.w = f2h(((const float*)&pre[3])[i]);
      *(ushort4*)&xs[(4 * tn4 + i) * 264 + colb] = wv4;
    }
  }
  __syncthreads();
  f32x4 acc[5][3] = {};
#pragma unroll
  for (int q = 0; q < 4; ++q) {
    // issue next quarter's loads before this quarter's MFMAs (latency hides)
    if (q < 3 && act) {
      const float* src = Xb + (size_t)((q + 1) * 64 + 4 * tcq) * NHW + tn4 * 4;
#pragma unroll
      for (int j = 0; j < 4; ++j) pre[j] = *(const float4*)(src + (size_t)j * NHW);
    }
#pragma unroll
    for (int kk = 2 * q; kk < 2 * q + 2; ++kk) {
      f16x8 a5[5], b3[3];
#pragma unroll
      for (int j = 0; j < 5; ++j) a5[j] = *(const f16x8*)(wrow[j] + kk * 32);
#pragma unroll
      for (int nt = 0; nt < 3; ++nt)
        b3[nt] = *(const f16x8*)&xs[rbase[nt] + ((kk * 32 + kc) ^ rsw[nt])];
#pragma unroll
      for (int j = 0; j < 5; ++j)
#pragma unroll
        for (int nt = 0; nt < 3; ++nt)
          acc[j][nt] = __builtin_amdgcn_mfma_f32_16x16x32_f16(a5[j], b3[nt], acc[j][nt], 0, 0, 0);
    }
    if (q < 3) {
      if (act) {  // write quarter q+1 (region untouched until after barrier)
        int colb = ((q + 1) * 64 + 4 * tcq) ^ ((tn4 & 7) << 3);
#pragma unroll
        for (int i = 0; i < 4; ++i) {
          ushort4 wv4;
          wv4.x = f2h(((const float*)&pre[0])[i]);
          wv4.y = f2h(((const float*)&pre[1])[i]);
          wv4.z = f2h(((const float*)&pre[2])[i]);
          wv4.w = f2h(((const float*)&pre[3])[i]);
          *(ushort4*)&xs[(4 * tn4 + i) * 264 + colb] = wv4;
        }
      }
      __syncthreads();
    }
  }
  __syncthreads();  // all xs reads done; sO overlay becomes safe
  // qk epilogue via LDS: sO[n][72] (n=0..95, o=0..63) then coalesced row stores
  {
    float4 bv = *(const float4*)(ball + mg * 16 + (g << 2));
    float ba[4] = {bv.x, bv.y, bv.z, bv.w};
#pragma unroll
    for (int nt = 0; nt < 3; ++nt) {
      int n = ng * 48 + nt * 16 + arow;
#pragma unroll
      for (int rr = 0; rr < 4; ++rr)
        sO[n * 72 + mg * 16 + (g << 2) + rr] = f2h(acc[0][nt][rr] + ba[rr]);
    }
    __syncthreads();
    u16* Ptb = Pt + (size_t)b * PT_BS + (size_t)h * 96 * 64;
    for (int idx = tid; idx < 768; idx += 512) {
      int n = idx >> 3, c8 = idx & 7;
      *(float4*)&Ptb[n * 64 + c8 * 8] = *(const float4*)&sO[n * 72 + c8 * 8];
    }
    __syncthreads();
  }
  // v epilogue: 2 rounds of 128 channels; round r covers v-tiles [8r, 8r+8)
  for (int r = 0; r < 2; ++r) {
#pragma unroll
    for (int jj = 0; jj < 2; ++jj) {
      int j = 2 * r + 1 + jj;          // acc row
      int vt = mg + 8 * r + 4 * jj;    // global v-tile (16 ch)
      float4 bv = *(const float4*)(ball + 64 + vt * 16 + (g << 2));
      float ba[4] = {bv.x, bv.y, bv.z, bv.w};
      int lrow0 = (mg + 4 * jj) * 16 + (g << 2);
#pragma unroll
      for (int nt = 0; nt < 3; ++nt) {
        int col = ng * 48 + nt * 16 + arow;
#pragma unroll
        for (int rr = 0; rr < 4; ++rr)
          sO[(lrow0 + rr) * 104 + col] = f2h(acc[j][nt][rr] + ba[rr]);
      }
    }
    __syncthreads();
    for (int idx = tid; idx < 1536; idx += 512) {
      int cc = idx / 12, c4 = idx % 12;
      *(float4*)(vW + ((size_t)(b * 96 + h) * 256 + r * 128 + cc) * 96 + c4 * 8) =
          *(const float4*)&sO[cc * 104 + c4 * 8];
    }
    __syncthreads();
  }
}

// vH[b][w][c][g] = vW[b][g][c][w], both pairs (z selects)
__global__ __launch_bounds__(256) void vtrans(const u16* __restrict__ vW0, const u16* __restrict__ vW1,
                                              u16* __restrict__ vH0, u16* __restrict__ vH1) {
  __shared__ u16 t[96][98];
  const int c = blockIdx.x, b = blockIdx.y;
  const u16* vWp = blockIdx.z ? vW1 : vW0;
  u16* vHp = blockIdx.z ? vH1 : vH0;
  for (int idx = threadIdx.x; idx < 4608; idx += 256) {
    int hh = idx / 48, w2 = idx % 48;
    *(unsigned int*)&t[hh][w2 * 2] =
        *(const unsigned int*)(vWp + (size_t)(b * 96 + hh) * 24576 + c * 96 + w2 * 2);
  }
  __syncthreads();
  for (int idx = threadIdx.x; idx < 4608; idx += 256) {
    int ww = idx / 48, g2 = idx % 48;
    unsigned int lo = t[g2 * 2][ww];
    unsigned int hi = t[g2 * 2 + 1][ww];
    *(unsigned int*)(vHp + (size_t)(b * 96 + ww) * 24576 + c * 96 + g2 * 2) = lo | (hi << 16);
  }
}

// attn: pass = z&1 (0: (b,h) e_w; 1: (b,w) e_h diag-masked), pair = z>>1.
__global__ __launch_bounds__(384, 3) void attn_fused(const u16* __restrict__ Pt0, const u16* __restrict__ Pt1,
                                                     const u16* __restrict__ vW0, const u16* __restrict__ vH0,
                                                     const u16* __restrict__ vW1, const u16* __restrict__ vH1,
                                                     float* __restrict__ mWs, float* __restrict__ sWs,
                                                     float* __restrict__ mHs, float* __restrict__ sHs,
                                                     u16* __restrict__ tmpW0, u16* __restrict__ tmpH0,
                                                     u16* __restrict__ tmpW1, u16* __restrict__ tmpH1) {
  __shared__ __align__(16) char smem[46592];
  u16* vbuf = (u16*)smem;             // [128][104]
  u16* qs = (u16*)smem;               // [96][40] overlays vbuf
  u16* ks = (u16*)(smem + 7680);      // [96][40]
  u16* probs = (u16*)(smem + 26624);  // [96][104]
  const int p = blockIdx.x, b = blockIdx.y, z = blockIdx.z;
  const int pass = z & 1, pair = z >> 1;
  const u16* Qpt = pair ? Pt0 : Pt1;  // pair0: q1,k0,v0 ; pair1: q0,k1,v1
  const u16* Kpt = pair ? Pt1 : Pt0;
  const u16* Vp = pair ? (pass ? vH1 : vW1) : (pass ? vH0 : vW0);
  u16* tOut = pair ? (pass ? tmpH1 : tmpW1) : (pass ? tmpH0 : tmpW0);
  float* mOut = (pass ? mHs : mWs) + (size_t)pair * (Bn * 9216);
  float* sOut = (pass ? sHs : sWs) + (size_t)pair * (Bn * 9216);
  const int tid = threadIdx.x;
  const size_t nbase = (size_t)b * PT_BS;
  const size_t rowoff = pass ? (size_t)p * 64 : (size_t)p * 6144;
  const int rstride = pass ? 6144 : 64;
  for (int idx = tid; idx < 768; idx += 384) {
    int i = idx >> 3, c8 = idx & 7;
    const u16* src = (c8 < 4)
        ? Qpt + nbase + rowoff + (size_t)i * rstride + c8 * 8
        : Kpt + nbase + rowoff + (size_t)i * rstride + 32 + (c8 - 4) * 8;
    float4 v = *(const float4*)src;
    u16* dst = (c8 < 4) ? &qs[i * 40 + c8 * 8] : &ks[i * 40 + (c8 - 4) * 8];
    *(float4*)dst = v;
  }
  __syncthreads();
  const int lane = tid & 63, wv = tid >> 6;
  const int cl = lane & 15, g = lane >> 4;
  const int kc = g * 8;
  const int w0 = wv * 16;
  f32x4 eacc[6];
  {
    f16x8 aq = *(const f16x8*)&qs[(w0 + cl) * 40 + kc];
#pragma unroll
    for (int nt = 0; nt < 6; ++nt) {
      f16x8 bk = *(const f16x8*)&ks[(nt * 16 + cl) * 40 + kc];
      f32x4 zz = {0.f, 0.f, 0.f, 0.f};
      eacc[nt] = __builtin_amdgcn_mfma_f32_16x16x32_f16(aq, bk, zz, 0, 0, 0);
    }
  }
#pragma unroll
  for (int r = 0; r < 4; ++r) {
    int i = w0 + 4 * g + r;
    float m = -1e30f;
#pragma unroll
    for (int nt = 0; nt < 6; ++nt) {
      float e = eacc[nt][r];
      if (pass && (nt * 16 + cl) == i) { e = -1e30f; eacc[nt][r] = e; }
      m = fmaxf(m, e);
    }
    m = fmaxf(m, __shfl_xor(m, 1));
    m = fmaxf(m, __shfl_xor(m, 2));
    m = fmaxf(m, __shfl_xor(m, 4));
    m = fmaxf(m, __shfl_xor(m, 8));
    float s = 0.f;
#pragma unroll
    for (int nt = 0; nt < 6; ++nt) {
      float pv = __expf(eacc[nt][r] - m);
      eacc[nt][r] = pv;
      s += pv;
    }
    s += __shfl_xor(s, 1);
    s += __shfl_xor(s, 2);
    s += __shfl_xor(s, 4);
    s += __shfl_xor(s, 8);
#pragma unroll
    for (int nt = 0; nt < 6; ++nt)
      probs[i * 104 + nt * 16 + cl] = f2h(eacc[nt][r]);
    if (cl == 0) {
      size_t sidx = pass ? ((size_t)(b * 96 + i) * 96 + p) : ((size_t)(b * 96 + p) * 96 + i);
      mOut[sidx] = m;
      sOut[sidx] = s;
    }
  }
  __syncthreads();
  f16x8 af[3];
#pragma unroll
  for (int kt = 0; kt < 3; ++kt)
    af[kt] = *(const f16x8*)&probs[(w0 + cl) * 104 + kt * 32 + kc];
  const size_t vbase = (size_t)(b * 96 + p) * 24576;
  for (int half = 0; half < 2; ++half) {
    for (int idx = tid; idx < 1536; idx += 384) {
      int r = idx / 12, c4 = idx % 12;
      *(float4*)&vbuf[r * 104 + c4 * 8] =
          *(const float4*)(Vp + vbase + (size_t)(half * 128 + r) * 96 + c4 * 8);
    }
    __syncthreads();
    f32x4 acc[8];
#pragma unroll
    for (int nt = 0; nt < 8; ++nt) {
      f32x4 a = {0.f, 0.f, 0.f, 0.f};
#pragma unroll
      for (int kt = 0; kt < 3; ++kt) {
        f16x8 bf = *(const f16x8*)&vbuf[(nt * 16 + cl) * 104 + kt * 32 + kc];
        a = __builtin_amdgcn_mfma_f32_16x16x32_f16(af[kt], bf, a, 0, 0, 0);
      }
      acc[nt] = a;
    }
    __syncthreads();
#pragma unroll
    for (int nt = 0; nt < 8; ++nt) {
      int c2 = nt * 16 + cl;
      int wr = w0 + (g << 2);
#pragma unroll
      for (int r = 0; r < 4; ++r) vbuf[c2 * 104 + wr + r] = f2h(acc[nt][r]);
    }
    __syncthreads();
    for (int idx = tid; idx < 1536; idx += 384) {
      int r = idx / 12, c4 = idx % 12;
      *(float4*)(tOut + vbase + (size_t)(half * 128 + r) * 96 + c4 * 8) =
          *(const float4*)&vbuf[r * 104 + c4 * 8];
    }
    __syncthreads();
  }
}

// Both pairs: i in [0, 2*Bn*9216)
__global__ __launch_bounds__(256) void scl_k(const float* __restrict__ mH, const float* __restrict__ sH,
                                             const float* __restrict__ mW, const float* __restrict__ sW,
                                             const float* __restrict__ gammaP, float* __restrict__ sclH,
                                             float* __restrict__ sclW) {
  int i = blockIdx.x * 256 + threadIdx.x;
  if (i >= 2 * Bn * 9216) return;
  float mh = mH[i], mw = mW[i];
  float m = fmaxf(mh, mw);
  float eh = __expf(mh - m), ew = __expf(mw - m);
  float s = sH[i] * eh + sW[i] * ew;
  float g = gammaP[0] / s;
  sclH[i] = g * eh;
  sclW[i] = g * ew;
}

// out[b][c][h][w] = x + tmpH[b][w][c][h]*sclH + tmpW[b][h][c][w]*sclW, pair = z
__global__ __launch_bounds__(256) void tkomb(const u16* __restrict__ tmpH0, const u16* __restrict__ tmpW0,
                                             const u16* __restrict__ tmpH1, const u16* __restrict__ tmpW1,
                                             const float* __restrict__ x0, const float* __restrict__ x1,
                                             const float* __restrict__ sclH, const float* __restrict__ sclW,
                                             float* __restrict__ out) {
  __shared__ u16 t[96][108];
  const int c = blockIdx.x, b = blockIdx.y, pr = blockIdx.z;
  const u16* tmpH = pr ? tmpH1 : tmpH0;
  const u16* tmpW = pr ? tmpW1 : tmpW0;
  const float* x = pr ? x1 : x0;
  const float* sH = sclH + (size_t)pr * (Bn * 9216);
  const float* sW = sclW + (size_t)pr * (Bn * 9216);
  float* o = out + (size_t)pr * Bn * Cn * NHW;
  const int tid = threadIdx.x;
  for (int idx = tid; idx < 2304; idx += 256) {
    int w_ = idx / 24, h4 = idx % 24;
    *(ushort4*)&t[w_][h4 * 4] =
        *(const ushort4*)(tmpH + ((size_t)(b * 96 + w_) * 256 + c) * 96 + h4 * 4);
  }
  __syncthreads();
  for (int idx = tid; idx < 2304; idx += 256) {
    int h_ = idx / 24, w4 = idx % 24;
    size_t go = ((size_t)(b * 256 + c) * 96 + h_) * 96 + w4 * 4;
    float4 xv = *(const float4*)(x + go);
    ushort4 wvv = *(const ushort4*)(tmpW + ((size_t)(b * 96 + h_) * 256 + c) * 96 + w4 * 4);
    float4 sh4 = *(const float4*)(sH + (size_t)(b * 96 + h_) * 96 + w4 * 4);
    float4 sw4 = *(const float4*)(sW + (size_t)(b * 96 + h_) * 96 + w4 * 4);
    float4 ov;
    ov.x = xv.x + h2f(t[w4 * 4 + 0][h_]) * sh4.x + h2f(wvv.x) * sw4.x;
    ov.y = xv.y + h2f(t[w4 * 4 + 1][h_]) * sh4.y + h2f(wvv.y) * sw4.y;
    ov.z = xv.z + h2f(t[w4 * 4 + 2][h_]) * sh4.z + h2f(wvv.z) * sw4.z;
    ov.w = xv.w + h2f(t[w4 * 4 + 3][h_]) * sh4.w + h2f(wvv.w) * sw4.w;
    *(float4*)(o + go) = ov;
  }
}

extern "C" void kernel_launch(void* const* d_in, const int* in_sizes, int n_in,
                              void* d_out, int out_size, void* d_ws, size_t ws_size,
                              hipStream_t stream) {
  const float* x0 = (const float*)d_in[0];
  const float* x1 = (const float*)d_in[1];
  const float* wq0 = (const float*)d_in[2];
  const float* bq0 = (const float*)d_in[3];
  const float* wk0 = (const float*)d_in[4];
  const float* bk0 = (const float*)d_in[5];
  const float* wv0 = (const float*)d_in[6];
  const float* bv0 = (const float*)d_in[7];
  const float* wq1 = (const float*)d_in[8];
  const float* bq1 = (const float*)d_in[9];
  const float* wk1 = (const float*)d_in[10];
  const float* bk1 = (const float*)d_in[11];
  const float* wv1 = (const float*)d_in[12];
  const float* bv1 = (const float*)d_in[13];
  const float* gamma = (const float*)d_in[14];
  float* out = (float*)d_out;

  char* ws = (char*)d_ws;
  size_t off = 0;
  auto alloc = [&](size_t bytes) -> void* {
    void* ptr = ws + off;
    off += (bytes + 255) & ~(size_t)255;
    return ptr;
  };
  const size_t SZ_P = (size_t)Bn * NHW * 64 * 2;   // 9.4 MB (f16)
  const size_t SZ_V = (size_t)Bn * NHW * Cn * 2;   // 37.7 MB
  const size_t SZ_S = (size_t)Bn * 9216 * 4;       // 294 KB
  u16* Pt0 = (u16*)alloc(SZ_P);
  u16* Pt1 = (u16*)alloc(SZ_P);
  u16* vW0 = (u16*)alloc(SZ_V);
  u16* vW1 = (u16*)alloc(SZ_V);
  u16* vH0 = (u16*)alloc(SZ_V);
  u16* vH1 = (u16*)alloc(SZ_V);
  u16* tmpW0 = (u16*)alloc(SZ_V);
  u16* tmpH0 = (u16*)alloc(SZ_V);
  u16* tmpW1 = (u16*)alloc(SZ_V);
  u16* tmpH1 = (u16*)alloc(SZ_V);
  u16* Wall0 = (u16*)alloc(320 * 256 * 2);
  u16* Wall1 = (u16*)alloc(320 * 256 * 2);
  float* ball0 = (float*)alloc(320 * 4);
  float* ball1 = (float*)alloc(320 * 4);
  float* mH = (float*)alloc(2 * SZ_S);
  float* sH = (float*)alloc(2 * SZ_S);
  float* mW = (float*)alloc(2 * SZ_S);
  float* sW = (float*)alloc(2 * SZ_S);
  float* sclH = (float*)alloc(2 * SZ_S);
  float* sclW = (float*)alloc(2 * SZ_S);
  (void)ws_size; (void)in_sizes; (void)n_in; (void)out_size;

  dim3 gpk(320, 2), gp(96, Bn, 2), gt(256, Bn, 2), ga(96, Bn, 4), gc(256, Bn, 2);
  pack_all<<<gpk, 256, 0, stream>>>(wq0, bq0, wk0, bk0, wv0, bv0,
                                    wq1, bq1, wk1, bk1, wv1, bv1,
                                    Wall0, ball0, Wall1, ball1);
  proj_all<<<gp, 512, 0, stream>>>(x0, x1, Wall0, Wall1, ball0, ball1, Pt0, Pt1, vW0, vW1);
  vtrans<<<gt, 256, 0, stream>>>(vW0, vW1, vH0, vH1);
  attn_fused<<<ga, 384, 0, stream>>>(Pt0, Pt1, vW0, vH0, vW1, vH1,
                                     mW, sW, mH, sH, tmpW0, tmpH0, tmpW1, tmpH1);
  scl_k<<<576, 256, 0, stream>>>(mH, sH, mW, sW, gamma, sclH, sclW);
  tkomb<<<gc, 256, 0, stream>>>(tmpH0, tmpW0, tmpH1, tmpW1, x0, x1, sclH, sclW, out);
}

// Round 15
// 332.327 us; speedup vs baseline: 1.0028x; 1.0028x over previous
//
#include <hip/hip_runtime.h>
#include <hip/hip_bf16.h>

// CrissCross attention, B=8 C=256 H=W=96 CQ=32. Flash-style split softmax, fp16.
// 6 dispatches total (pairs merged via blockIdx.z everywhere):
//  pack_all : [wq|wk|wv] -> f16 Wall[320][256] + fp32 ball[320], both inputs
//  proj_all : 256-thr 4-wave f16-MFMA blocks, BN=48 (R14 lesson: TLP, not
//             register budget, is the lever): ~25KB LDS -> 4+ blocks/CU.
//             K-quarter pipelined staging (R13) + swizzled LDS (R11).
//             -> Pt[b][n][64] f16 + vW[b][h][c][w] f16
//  vtrans   : vW* -> vH*[b][w][c][g]
//  attn     : z&1: 0 = (b,h) e_w pass, 1 = (b,w) e_h pass (diag mask); z>>1 = pair.
//             LDS-staged q/k, MFMA QK^T, in-reg wave softmax, staged V halves,
//             PV MFMA, LDS-transposed coalesced stores.
//  scl      : exact concat-softmax rescale (gamma folded), both pairs
//  tkomb    : out = x + tmpH^T*sclH + tmpW*sclW (transpose fused), both pairs

#define Bn 8
#define Cn 256
#define NHW 9216
#define PT_BS ((size_t)NHW * 64)

typedef unsigned short u16;
typedef __attribute__((ext_vector_type(8))) _Float16 f16x8;
typedef __attribute__((ext_vector_type(4))) float f32x4;

__device__ __forceinline__ float h2f(u16 v) {
  _Float16 h;
  __builtin_memcpy(&h, &v, 2);
  return (float)h;
}
__device__ __forceinline__ u16 f2h(float f) {
  _Float16 h = (_Float16)f;
  u16 v;
  __builtin_memcpy(&v, &h, 2);
  return v;
}

__global__ __launch_bounds__(256) void pack_all(const float* __restrict__ wq0, const float* __restrict__ bq0,
                                                const float* __restrict__ wk0, const float* __restrict__ bk0,
                                                const float* __restrict__ wv0, const float* __restrict__ bv0,
                                                const float* __restrict__ wq1, const float* __restrict__ bq1,
                                                const float* __restrict__ wk1, const float* __restrict__ bk1,
                                                const float* __restrict__ wv1, const float* __restrict__ bv1,
                                                u16* __restrict__ Wall0, float* __restrict__ ball0,
                                                u16* __restrict__ Wall1, float* __restrict__ ball1) {
  const int pr = blockIdx.y;
  const float* wq = pr ? wq1 : wq0;
  const float* bq = pr ? bq1 : bq0;
  const float* wk = pr ? wk1 : wk0;
  const float* bk = pr ? bk1 : bk0;
  const float* wv = pr ? wv1 : wv0;
  const float* bv = pr ? bv1 : bv0;
  u16* Wall = pr ? Wall1 : Wall0;
  float* ball = pr ? ball1 : ball0;
  int i = blockIdx.x * 256 + threadIdx.x;
  if (i < 320 * 256) {
    int o = i >> 8, c = i & 255;
    float v = (o < 32) ? wq[o * 256 + c] : (o < 64) ? wk[(o - 32) * 256 + c] : wv[(o - 64) * 256 + c];
    Wall[i] = f2h(v);
  }
  if (i < 320) ball[i] = (i < 32) ? bq[i] : (i < 64) ? bk[i - 32] : bv[i - 64];
}

// Fused projection: block (h2, b, pair); h = h2>>1, w-cols [(h2&1)*48, +48).
// 256 threads = 4 waves; wave mg owns m-tiles {mg+4j, j=0..4} (j=0 -> qk tile),
// n-tiles {0,16,32} of the 48-col slab.
// xs element (row n, col k) at xs[row*264 + (col ^ (((row>>2)&7)<<3))].
// Staging pipelined over 4 K-quarters: issue q+1 loads -> 2 kk-steps of q ->
// write regs -> barrier. 192 staging tasks (tid<192).
__global__ __launch_bounds__(256, 4) void proj_all(const float* __restrict__ X0, const float* __restrict__ X1,
                                                   const u16* __restrict__ Wall0, const u16* __restrict__ Wall1,
                                                   const float* __restrict__ ball0, const float* __restrict__ ball1,
                                                   u16* __restrict__ Pt0, u16* __restrict__ Pt1,
                                                   u16* __restrict__ vW0, u16* __restrict__ vW1) {
  __shared__ __align__(16) u16 xs[48 * 264];  // 25344 B, swizzled [n][cin]
  u16* sO = xs;                               // overlay [128][56] for v epilogue
  const int h2 = blockIdx.x, b = blockIdx.y, pr = blockIdx.z;
  const int h = h2 >> 1, wc0 = (h2 & 1) * 48;
  const float* X = pr ? X1 : X0;
  const u16* Wall = pr ? Wall1 : Wall0;
  const float* ball = pr ? ball1 : ball0;
  u16* Pt = pr ? Pt1 : Pt0;
  u16* vW = pr ? vW1 : vW0;
  const int tid = threadIdx.x;
  const float* Xb = X + (size_t)b * Cn * NHW + h * 96 + wc0;
  // staging task (per quarter): 192 tasks = 16 tcq (4-cin quads) x 12 tn4 (4-n quads)
  const int tcq = tid / 12, tn4 = tid % 12;
  const bool act = tid < 192;
  const int lane = tid & 63, mg = tid >> 6;  // waves 0..3
  const int arow = lane & 15;
  const int g = lane >> 4;
  const int kc = g * 8;
  const u16* wrow[5];
#pragma unroll
  for (int j = 0; j < 5; ++j)
    wrow[j] = Wall + (size_t)((mg + 4 * j) * 16 + arow) * 256 + kc;
  int rbase[3], rsw[3];
#pragma unroll
  for (int nt = 0; nt < 3; ++nt) {
    int row = nt * 16 + arow;
    rbase[nt] = row * 264;
    rsw[nt] = ((row >> 2) & 7) << 3;
  }
  float4 pre[4];
  // prologue: load + write quarter 0
  if (act) {
    const float* src = Xb + (size_t)(4 * tcq) * NHW + tn4 * 4;
#pragma unroll
    for (int j = 0; j < 4; ++j) pre[j] = *(const float4*)(src + (size_t)j * NHW);
    int colb = (4 * tcq) ^ ((tn4 & 7) << 3);
#pragma unroll
    for (int i = 0; i < 4; ++i) {
      ushort4 wv4;
      wv4.x = f2h(((const float*)&pre[0])[i]);
      wv4.y = f2h(((const float*)&pre[1])[i]);
      wv4.z = f2h(((const float*)&pre[2])[i]);
      wv4.w = f2h(((const float*)&pre[3])[i]);
      *(ushort4*)&xs[(4 * tn4 + i) * 264 + colb] = wv4;
    }
  }
  __syncthreads();
  f32x4 acc[5][3] = {};
#pragma unroll
  for (int q = 0; q < 4; ++q) {
    if (q < 3 && act) {  // issue next quarter's loads before this quarter's MFMAs
      const float* src = Xb + (size_t)((q + 1) * 64 + 4 * tcq) * NHW + tn4 * 4;
#pragma unroll
      for (int j = 0; j < 4; ++j) pre[j] = *(const float4*)(src + (size_t)j * NHW);
    }
#pragma unroll
    for (int kk = 2 * q; kk < 2 * q + 2; ++kk) {
      f16x8 a5[5], b3[3];
#pragma unroll
      for (int j = 0; j < 5; ++j) a5[j] = *(const f16x8*)(wrow[j] + kk * 32);
#pragma unroll
      for (int nt = 0; nt < 3; ++nt)
        b3[nt] = *(const f16x8*)&xs[rbase[nt] + ((kk * 32 + kc) ^ rsw[nt])];
#pragma unroll
      for (int j = 0; j < 5; ++j)
#pragma unroll
        for (int nt = 0; nt < 3; ++nt)
          acc[j][nt] = __builtin_amdgcn_mfma_f32_16x16x32_f16(a5[j], b3[nt], acc[j][nt], 0, 0, 0);
    }
    if (q < 3) {
      if (act) {  // write quarter q+1 (region untouched until after barrier)
        int colb = ((q + 1) * 64 + 4 * tcq) ^ ((tn4 & 7) << 3);
#pragma unroll
        for (int i = 0; i < 4; ++i) {
          ushort4 wv4;
          wv4.x = f2h(((const float*)&pre[0])[i]);
          wv4.y = f2h(((const float*)&pre[1])[i]);
          wv4.z = f2h(((const float*)&pre[2])[i]);
          wv4.w = f2h(((const float*)&pre[3])[i]);
          *(ushort4*)&xs[(4 * tn4 + i) * 264 + colb] = wv4;
        }
      }
      __syncthreads();
    }
  }
  // qk epilogue: o = mg*16 + 4g + rr; n = h2*48 + nt*16 + arow (direct stores)
  {
    u16* Ptb = Pt + (size_t)b * PT_BS;
    float4 bv = *(const float4*)(ball + mg * 16 + (g << 2));
#pragma unroll
    for (int nt = 0; nt < 3; ++nt) {
      int n = h2 * 48 + nt * 16 + arow;
      f32x4 a = acc[0][nt];
      ushort4 r;
      r.x = f2h(a[0] + bv.x); r.y = f2h(a[1] + bv.y);
      r.z = f2h(a[2] + bv.z); r.w = f2h(a[3] + bv.w);
      *(ushort4*)&Ptb[(size_t)n * 64 + mg * 16 + (g << 2)] = r;
    }
  }
  __syncthreads();
  // v epilogue: 2 rounds of 128 channels; round r covers v-tiles [8r, 8r+8).
  // Wave mg writes acc rows j=2r+1+jj -> tile mg+8r+4jj, local row (mg+4jj)*16+4g.
  for (int r = 0; r < 2; ++r) {
#pragma unroll
    for (int jj = 0; jj < 2; ++jj) {
      int j = 2 * r + 1 + jj;
      int vt = mg + 8 * r + 4 * jj;
      float4 bv = *(const float4*)(ball + 64 + vt * 16 + (g << 2));
      float ba[4] = {bv.x, bv.y, bv.z, bv.w};
      int lrow0 = (mg + 4 * jj) * 16 + (g << 2);
#pragma unroll
      for (int nt = 0; nt < 3; ++nt) {
        int col = nt * 16 + arow;
#pragma unroll
        for (int rr = 0; rr < 4; ++rr)
          sO[(lrow0 + rr) * 56 + col] = f2h(acc[j][nt][rr] + ba[rr]);
      }
    }
    __syncthreads();
    for (int idx = tid; idx < 768; idx += 256) {
      int cc = idx / 6, c4 = idx % 6;
      *(float4*)(vW + ((size_t)(b * 96 + h) * 256 + r * 128 + cc) * 96 + wc0 + c4 * 8) =
          *(const float4*)&sO[cc * 56 + c4 * 8];
    }
    __syncthreads();
  }
}

// vH[b][w][c][g] = vW[b][g][c][w], both pairs (z selects)
__global__ __launch_bounds__(256) void vtrans(const u16* __restrict__ vW0, const u16* __restrict__ vW1,
                                              u16* __restrict__ vH0, u16* __restrict__ vH1) {
  __shared__ u16 t[96][98];
  const int c = blockIdx.x, b = blockIdx.y;
  const u16* vWp = blockIdx.z ? vW1 : vW0;
  u16* vHp = blockIdx.z ? vH1 : vH0;
  for (int idx = threadIdx.x; idx < 4608; idx += 256) {
    int hh = idx / 48, w2 = idx % 48;
    *(unsigned int*)&t[hh][w2 * 2] =
        *(const unsigned int*)(vWp + (size_t)(b * 96 + hh) * 24576 + c * 96 + w2 * 2);
  }
  __syncthreads();
  for (int idx = threadIdx.x; idx < 4608; idx += 256) {
    int ww = idx / 48, g2 = idx % 48;
    unsigned int lo = t[g2 * 2][ww];
    unsigned int hi = t[g2 * 2 + 1][ww];
    *(unsigned int*)(vHp + (size_t)(b * 96 + ww) * 24576 + c * 96 + g2 * 2) = lo | (hi << 16);
  }
}

// attn: pass = z&1 (0: (b,h) e_w; 1: (b,w) e_h diag-masked), pair = z>>1.
__global__ __launch_bounds__(384, 3) void attn_fused(const u16* __restrict__ Pt0, const u16* __restrict__ Pt1,
                                                     const u16* __restrict__ vW0, const u16* __restrict__ vH0,
                                                     const u16* __restrict__ vW1, const u16* __restrict__ vH1,
                                                     float* __restrict__ mWs, float* __restrict__ sWs,
                                                     float* __restrict__ mHs, float* __restrict__ sHs,
                                                     u16* __restrict__ tmpW0, u16* __restrict__ tmpH0,
                                                     u16* __restrict__ tmpW1, u16* __restrict__ tmpH1) {
  __shared__ __align__(16) char smem[46592];
  u16* vbuf = (u16*)smem;             // [128][104]
  u16* qs = (u16*)smem;               // [96][40] overlays vbuf
  u16* ks = (u16*)(smem + 7680);      // [96][40]
  u16* probs = (u16*)(smem + 26624);  // [96][104]
  const int p = blockIdx.x, b = blockIdx.y, z = blockIdx.z;
  const int pass = z & 1, pair = z >> 1;
  const u16* Qpt = pair ? Pt0 : Pt1;  // pair0: q1,k0,v0 ; pair1: q0,k1,v1
  const u16* Kpt = pair ? Pt1 : Pt0;
  const u16* Vp = pair ? (pass ? vH1 : vW1) : (pass ? vH0 : vW0);
  u16* tOut = pair ? (pass ? tmpH1 : tmpW1) : (pass ? tmpH0 : tmpW0);
  float* mOut = (pass ? mHs : mWs) + (size_t)pair * (Bn * 9216);
  float* sOut = (pass ? sHs : sWs) + (size_t)pair * (Bn * 9216);
  const int tid = threadIdx.x;
  const size_t nbase = (size_t)b * PT_BS;
  const size_t rowoff = pass ? (size_t)p * 64 : (size_t)p * 6144;
  const int rstride = pass ? 6144 : 64;
  for (int idx = tid; idx < 768; idx += 384) {
    int i = idx >> 3, c8 = idx & 7;
    const u16* src = (c8 < 4)
        ? Qpt + nbase + rowoff + (size_t)i * rstride + c8 * 8
        : Kpt + nbase + rowoff + (size_t)i * rstride + 32 + (c8 - 4) * 8;
    float4 v = *(const float4*)src;
    u16* dst = (c8 < 4) ? &qs[i * 40 + c8 * 8] : &ks[i * 40 + (c8 - 4) * 8];
    *(float4*)dst = v;
  }
  __syncthreads();
  const int lane = tid & 63, wv = tid >> 6;
  const int cl = lane & 15, g = lane >> 4;
  const int kc = g * 8;
  const int w0 = wv * 16;
  f32x4 eacc[6];
  {
    f16x8 aq = *(const f16x8*)&qs[(w0 + cl) * 40 + kc];
#pragma unroll
    for (int nt = 0; nt < 6; ++nt) {
      f16x8 bk = *(const f16x8*)&ks[(nt * 16 + cl) * 40 + kc];
      f32x4 zz = {0.f, 0.f, 0.f, 0.f};
      eacc[nt] = __builtin_amdgcn_mfma_f32_16x16x32_f16(aq, bk, zz, 0, 0, 0);
    }
  }
#pragma unroll
  for (int r = 0; r < 4; ++r) {
    int i = w0 + 4 * g + r;
    float m = -1e30f;
#pragma unroll
    for (int nt = 0; nt < 6; ++nt) {
      float e = eacc[nt][r];
      if (pass && (nt * 16 + cl) == i) { e = -1e30f; eacc[nt][r] = e; }
      m = fmaxf(m, e);
    }
    m = fmaxf(m, __shfl_xor(m, 1));
    m = fmaxf(m, __shfl_xor(m, 2));
    m = fmaxf(m, __shfl_xor(m, 4));
    m = fmaxf(m, __shfl_xor(m, 8));
    float s = 0.f;
#pragma unroll
    for (int nt = 0; nt < 6; ++nt) {
      float pv = __expf(eacc[nt][r] - m);
      eacc[nt][r] = pv;
      s += pv;
    }
    s += __shfl_xor(s, 1);
    s += __shfl_xor(s, 2);
    s += __shfl_xor(s, 4);
    s += __shfl_xor(s, 8);
#pragma unroll
    for (int nt = 0; nt < 6; ++nt)
      probs[i * 104 + nt * 16 + cl] = f2h(eacc[nt][r]);
    if (cl == 0) {
      size_t sidx = pass ? ((size_t)(b * 96 + i) * 96 + p) : ((size_t)(b * 96 + p) * 96 + i);
      mOut[sidx] = m;
      sOut[sidx] = s;
    }
  }
  __syncthreads();
  f16x8 af[3];
#pragma unroll
  for (int kt = 0; kt < 3; ++kt)
    af[kt] = *(const f16x8*)&probs[(w0 + cl) * 104 + kt * 32 + kc];
  const size_t vbase = (size_t)(b * 96 + p) * 24576;
  for (int half = 0; half < 2; ++half) {
    for (int idx = tid; idx < 1536; idx += 384) {
      int r = idx / 12, c4 = idx % 12;
      *(float4*)&vbuf[r * 104 + c4 * 8] =
          *(const float4*)(Vp + vbase + (size_t)(half * 128 + r) * 96 + c4 * 8);
    }
    __syncthreads();
    f32x4 acc[8];
#pragma unroll
    for (int nt = 0; nt < 8; ++nt) {
      f32x4 a = {0.f, 0.f, 0.f, 0.f};
#pragma unroll
      for (int kt = 0; kt < 3; ++kt) {
        f16x8 bf = *(const f16x8*)&vbuf[(nt * 16 + cl) * 104 + kt * 32 + kc];
        a = __builtin_amdgcn_mfma_f32_16x16x32_f16(af[kt], bf, a, 0, 0, 0);
      }
      acc[nt] = a;
    }
    __syncthreads();
#pragma unroll
    for (int nt = 0; nt < 8; ++nt) {
      int c2 = nt * 16 + cl;
      int wr = w0 + (g << 2);
#pragma unroll
      for (int r = 0; r < 4; ++r) vbuf[c2 * 104 + wr + r] = f2h(acc[nt][r]);
    }
    __syncthreads();
    for (int idx = tid; idx < 1536; idx += 384) {
      int r = idx / 12, c4 = idx % 12;
      *(float4*)(tOut + vbase + (size_t)(half * 128 + r) * 96 + c4 * 8) =
          *(const float4*)&vbuf[r * 104 + c4 * 8];
    }
    __syncthreads();
  }
}

// Both pairs: i in [0, 2*Bn*9216)
__global__ __launch_bounds__(256) void scl_k(const float* __restrict__ mH, const float* __restrict__ sH,
                                             const float* __restrict__ mW, const float* __restrict__ sW,
                                             const float* __restrict__ gammaP, float* __restrict__ sclH,
                                             float* __restrict__ sclW) {
  int i = blockIdx.x * 256 + threadIdx.x;
  if (i >= 2 * Bn * 9216) return;
  float mh = mH[i], mw = mW[i];
  float m = fmaxf(mh, mw);
  float eh = __expf(mh - m), ew = __expf(mw - m);
  float s = sH[i] * eh + sW[i] * ew;
  float g = gammaP[0] / s;
  sclH[i] = g * eh;
  sclW[i] = g * ew;
}

// out[b][c][h][w] = x + tmpH[b][w][c][h]*sclH + tmpW[b][h][c][w]*sclW, pair = z
__global__ __launch_bounds__(256) void tkomb(const u16* __restrict__ tmpH0, const u16* __restrict__ tmpW0,
                                             const u16* __restrict__ tmpH1, const u16* __restrict__ tmpW1,
                                             const float* __restrict__ x0, const float* __restrict__ x1,
                                             const float* __restrict__ sclH, const float* __restrict__ sclW,
                                             float* __restrict__ out) {
  __shared__ u16 t[96][108];
  const int c = blockIdx.x, b = blockIdx.y, pr = blockIdx.z;
  const u16* tmpH = pr ? tmpH1 : tmpH0;
  const u16* tmpW = pr ? tmpW1 : tmpW0;
  const float* x = pr ? x1 : x0;
  const float* sH = sclH + (size_t)pr * (Bn * 9216);
  const float* sW = sclW + (size_t)pr * (Bn * 9216);
  float* o = out + (size_t)pr * Bn * Cn * NHW;
  const int tid = threadIdx.x;
  for (int idx = tid; idx < 2304; idx += 256) {
    int w_ = idx / 24, h4 = idx % 24;
    *(ushort4*)&t[w_][h4 * 4] =
        *(const ushort4*)(tmpH + ((size_t)(b * 96 + w_) * 256 + c) * 96 + h4 * 4);
  }
  __syncthreads();
  for (int idx = tid; idx < 2304; idx += 256) {
    int h_ = idx / 24, w4 = idx % 24;
    size_t go = ((size_t)(b * 256 + c) * 96 + h_) * 96 + w4 * 4;
    float4 xv = *(const float4*)(x + go);
    ushort4 wvv = *(const ushort4*)(tmpW + ((size_t)(b * 96 + h_) * 256 + c) * 96 + w4 * 4);
    float4 sh4 = *(const float4*)(sH + (size_t)(b * 96 + h_) * 96 + w4 * 4);
    float4 sw4 = *(const float4*)(sW + (size_t)(b * 96 + h_) * 96 + w4 * 4);
    float4 ov;
    ov.x = xv.x + h2f(t[w4 * 4 + 0][h_]) * sh4.x + h2f(wvv.x) * sw4.x;
    ov.y = xv.y + h2f(t[w4 * 4 + 1][h_]) * sh4.y + h2f(wvv.y) * sw4.y;
    ov.z = xv.z + h2f(t[w4 * 4 + 2][h_]) * sh4.z + h2f(wvv.z) * sw4.z;
    ov.w = xv.w + h2f(t[w4 * 4 + 3][h_]) * sh4.w + h2f(wvv.w) * sw4.w;
    *(float4*)(o + go) = ov;
  }
}

extern "C" void kernel_launch(void* const* d_in, const int* in_sizes, int n_in,
                              void* d_out, int out_size, void* d_ws, size_t ws_size,
                              hipStream_t stream) {
  const float* x0 = (const float*)d_in[0];
  const float* x1 = (const float*)d_in[1];
  const float* wq0 = (const float*)d_in[2];
  const float* bq0 = (const float*)d_in[3];
  const float* wk0 = (const float*)d_in[4];
  const float* bk0 = (const float*)d_in[5];
  const float* wv0 = (const float*)d_in[6];
  const float* bv0 = (const float*)d_in[7];
  const float* wq1 = (const float*)d_in[8];
  const float* bq1 = (const float*)d_in[9];
  const float* wk1 = (const float*)d_in[10];
  const float* bk1 = (const float*)d_in[11];
  const float* wv1 = (const float*)d_in[12];
  const float* bv1 = (const float*)d_in[13];
  const float* gamma = (const float*)d_in[14];
  float* out = (float*)d_out;

  char* ws = (char*)d_ws;
  size_t off = 0;
  auto alloc = [&](size_t bytes) -> void* {
    void* ptr = ws + off;
    off += (bytes + 255) & ~(size_t)255;
    return ptr;
  };
  const size_t SZ_P = (size_t)Bn * NHW * 64 * 2;   // 9.4 MB (f16)
  const size_t SZ_V = (size_t)Bn * NHW * Cn * 2;   // 37.7 MB
  const size_t SZ_S = (size_t)Bn * 9216 * 4;       // 294 KB
  u16* Pt0 = (u16*)alloc(SZ_P);
  u16* Pt1 = (u16*)alloc(SZ_P);
  u16* vW0 = (u16*)alloc(SZ_V);
  u16* vW1 = (u16*)alloc(SZ_V);
  u16* vH0 = (u16*)alloc(SZ_V);
  u16* vH1 = (u16*)alloc(SZ_V);
  u16* tmpW0 = (u16*)alloc(SZ_V);
  u16* tmpH0 = (u16*)alloc(SZ_V);
  u16* tmpW1 = (u16*)alloc(SZ_V);
  u16* tmpH1 = (u16*)alloc(SZ_V);
  u16* Wall0 = (u16*)alloc(320 * 256 * 2);
  u16* Wall1 = (u16*)alloc(320 * 256 * 2);
  float* ball0 = (float*)alloc(320 * 4);
  float* ball1 = (float*)alloc(320 * 4);
  float* mH = (float*)alloc(2 * SZ_S);
  float* sH = (float*)alloc(2 * SZ_S);
  float* mW = (float*)alloc(2 * SZ_S);
  float* sW = (float*)alloc(2 * SZ_S);
  float* sclH = (float*)alloc(2 * SZ_S);
  float* sclW = (float*)alloc(2 * SZ_S);
  (void)ws_size; (void)in_sizes; (void)n_in; (void)out_size;

  dim3 gpk(320, 2), gp(192, Bn, 2), gt(256, Bn, 2), ga(96, Bn, 4), gc(256, Bn, 2);
  pack_all<<<gpk, 256, 0, stream>>>(wq0, bq0, wk0, bk0, wv0, bv0,
                                    wq1, bq1, wk1, bk1, wv1, bv1,
                                    Wall0, ball0, Wall1, ball1);
  proj_all<<<gp, 256, 0, stream>>>(x0, x1, Wall0, Wall1, ball0, ball1, Pt0, Pt1, vW0, vW1);
  vtrans<<<gt, 256, 0, stream>>>(vW0, vW1, vH0, vH1);
  attn_fused<<<ga, 384, 0, stream>>>(Pt0, Pt1, vW0, vH0, vW1, vH1,
                                     mW, sW, mH, sH, tmpW0, tmpH0, tmpW1, tmpH1);
  scl_k<<<576, 256, 0, stream>>>(mH, sH, mW, sW, gamma, sclH, sclW);
  tkomb<<<gc, 256, 0, stream>>>(tmpH0, tmpW0, tmpH1, tmpW1, x0, x1, sclH, sclW, out);
}

// Round 17
// 291.944 us; speedup vs baseline: 1.1415x; 1.1383x over previous
//
#include <hip/hip_runtime.h>
#include <hip/hip_bf16.h>

// CrissCross attention, B=8 C=256 H=W=96 CQ=32. Flash-style split softmax, fp16.
// 5 dispatches (pairs merged via blockIdx.z):
//  pack_all : [wq|wk|wv] -> f16 Wall[320][256] + fp32 ball[320], both inputs
//  proj_all : R13-best: 512-thr 8-wave f16-MFMA, K-quarter pipelined staging,
//             swizzled LDS -> Pt[b][n][64] f16 + vW[b][h][c][w] f16
//  vtrans   : vW* -> vH*[b][w][c][g]
//  attn1    : e_h pass only (diag mask), per (b,w): MFMA QK^T, in-reg softmax,
//             stats (mH,sH), PV -> tmpHt[b][w][h][c] (TRANSPOSED store, 256B runs)
//  pv_comb  : per (b,h): QK^T(e_w), local stats + read (mH,sH) -> exact
//             concat-softmax scale folded into probs; PV (vW); results held in
//             registers; tmpHt slab staged to LDS; writes
//             out = x + outw + tmpHt*sclH directly (tmpW/scl/tkomb eliminated).
// R16 fix: both half-channel indexing bugs (attn1 tOut store 768->1536 tasks,
// pv_comb ttile staging 1536->3072 tasks) that left channels 64+/128+ garbage.

#define Bn 8
#define Cn 256
#define NHW 9216
#define PT_BS ((size_t)NHW * 64)

typedef unsigned short u16;
typedef __attribute__((ext_vector_type(8))) _Float16 f16x8;
typedef __attribute__((ext_vector_type(4))) float f32x4;

__device__ __forceinline__ float h2f(u16 v) {
  _Float16 h;
  __builtin_memcpy(&h, &v, 2);
  return (float)h;
}
__device__ __forceinline__ u16 f2h(float f) {
  _Float16 h = (_Float16)f;
  u16 v;
  __builtin_memcpy(&v, &h, 2);
  return v;
}

__global__ __launch_bounds__(256) void pack_all(const float* __restrict__ wq0, const float* __restrict__ bq0,
                                                const float* __restrict__ wk0, const float* __restrict__ bk0,
                                                const float* __restrict__ wv0, const float* __restrict__ bv0,
                                                const float* __restrict__ wq1, const float* __restrict__ bq1,
                                                const float* __restrict__ wk1, const float* __restrict__ bk1,
                                                const float* __restrict__ wv1, const float* __restrict__ bv1,
                                                u16* __restrict__ Wall0, float* __restrict__ ball0,
                                                u16* __restrict__ Wall1, float* __restrict__ ball1) {
  const int pr = blockIdx.y;
  const float* wq = pr ? wq1 : wq0;
  const float* bq = pr ? bq1 : bq0;
  const float* wk = pr ? wk1 : wk0;
  const float* bk = pr ? bk1 : bk0;
  const float* wv = pr ? wv1 : wv0;
  const float* bv = pr ? bv1 : bv0;
  u16* Wall = pr ? Wall1 : Wall0;
  float* ball = pr ? ball1 : ball0;
  int i = blockIdx.x * 256 + threadIdx.x;
  if (i < 320 * 256) {
    int o = i >> 8, c = i & 255;
    float v = (o < 32) ? wq[o * 256 + c] : (o < 64) ? wk[(o - 32) * 256 + c] : wv[(o - 64) * 256 + c];
    Wall[i] = f2h(v);
  }
  if (i < 320) ball[i] = (i < 32) ? bq[i] : (i < 64) ? bk[i - 32] : bv[i - 64];
}

// R13 proj: block (h, b, pair). 512 threads = 8 waves (mg = wv>>1, ng = wv&1).
__global__ __launch_bounds__(512, 4) void proj_all(const float* __restrict__ X0, const float* __restrict__ X1,
                                                   const u16* __restrict__ Wall0, const u16* __restrict__ Wall1,
                                                   const float* __restrict__ ball0, const float* __restrict__ ball1,
                                                   u16* __restrict__ Pt0, u16* __restrict__ Pt1,
                                                   u16* __restrict__ vW0, u16* __restrict__ vW1) {
  __shared__ __align__(16) u16 xs[96 * 264];  // 50688 B, swizzled [n][cin]
  u16* sO = xs;                               // overlay [128][104] for v epilogue
  const int h = blockIdx.x, b = blockIdx.y, pr = blockIdx.z;
  const float* X = pr ? X1 : X0;
  const u16* Wall = pr ? Wall1 : Wall0;
  const float* ball = pr ? ball1 : ball0;
  u16* Pt = pr ? Pt1 : Pt0;
  u16* vW = pr ? vW1 : vW0;
  const int tid = threadIdx.x;
  const float* Xb = X + (size_t)b * Cn * NHW + h * 96;
  const int tcq = tid / 24, tn4 = tid % 24;
  const bool act = tid < 384;
  const int lane = tid & 63, wv = tid >> 6;
  const int mg = wv >> 1, ng = wv & 1;
  const int arow = lane & 15;
  const int g = lane >> 4;
  const int kc = g * 8;
  const u16* wrow[5];
#pragma unroll
  for (int j = 0; j < 5; ++j)
    wrow[j] = Wall + (size_t)((mg + 4 * j) * 16 + arow) * 256 + kc;
  int rbase[3], rsw[3];
#pragma unroll
  for (int nt = 0; nt < 3; ++nt) {
    int row = ng * 48 + nt * 16 + arow;
    rbase[nt] = row * 264;
    rsw[nt] = ((row >> 2) & 7) << 3;
  }
  float4 pre[4];
  if (act) {
    const float* src = Xb + (size_t)(4 * tcq) * NHW + tn4 * 4;
#pragma unroll
    for (int j = 0; j < 4; ++j) pre[j] = *(const float4*)(src + (size_t)j * NHW);
    int colb = (4 * tcq) ^ ((tn4 & 7) << 3);
#pragma unroll
    for (int i = 0; i < 4; ++i) {
      ushort4 wv4;
      wv4.x = f2h(((const float*)&pre[0])[i]);
      wv4.y = f2h(((const float*)&pre[1])[i]);
      wv4.z = f2h(((const float*)&pre[2])[i]);
      wv4.w = f2h(((const float*)&pre[3])[i]);
      *(ushort4*)&xs[(4 * tn4 + i) * 264 + colb] = wv4;
    }
  }
  __syncthreads();
  f32x4 acc[5][3] = {};
#pragma unroll
  for (int q = 0; q < 4; ++q) {
    if (q < 3 && act) {
      const float* src = Xb + (size_t)((q + 1) * 64 + 4 * tcq) * NHW + tn4 * 4;
#pragma unroll
      for (int j = 0; j < 4; ++j) pre[j] = *(const float4*)(src + (size_t)j * NHW);
    }
#pragma unroll
    for (int kk = 2 * q; kk < 2 * q + 2; ++kk) {
      f16x8 a5[5], b3[3];
#pragma unroll
      for (int j = 0; j < 5; ++j) a5[j] = *(const f16x8*)(wrow[j] + kk * 32);
#pragma unroll
      for (int nt = 0; nt < 3; ++nt)
        b3[nt] = *(const f16x8*)&xs[rbase[nt] + ((kk * 32 + kc) ^ rsw[nt])];
#pragma unroll
      for (int j = 0; j < 5; ++j)
#pragma unroll
        for (int nt = 0; nt < 3; ++nt)
          acc[j][nt] = __builtin_amdgcn_mfma_f32_16x16x32_f16(a5[j], b3[nt], acc[j][nt], 0, 0, 0);
    }
    if (q < 3) {
      if (act) {
        int colb = ((q + 1) * 64 + 4 * tcq) ^ ((tn4 & 7) << 3);
#pragma unroll
        for (int i = 0; i < 4; ++i) {
          ushort4 wv4;
          wv4.x = f2h(((const float*)&pre[0])[i]);
          wv4.y = f2h(((const float*)&pre[1])[i]);
          wv4.z = f2h(((const float*)&pre[2])[i]);
          wv4.w = f2h(((const float*)&pre[3])[i]);
          *(ushort4*)&xs[(4 * tn4 + i) * 264 + colb] = wv4;
        }
      }
      __syncthreads();
    }
  }
  {
    u16* Ptb = Pt + (size_t)b * PT_BS;
    float4 bv = *(const float4*)(ball + mg * 16 + (g << 2));
#pragma unroll
    for (int nt = 0; nt < 3; ++nt) {
      int n = h * 96 + ng * 48 + nt * 16 + arow;
      f32x4 a = acc[0][nt];
      ushort4 r;
      r.x = f2h(a[0] + bv.x); r.y = f2h(a[1] + bv.y);
      r.z = f2h(a[2] + bv.z); r.w = f2h(a[3] + bv.w);
      *(ushort4*)&Ptb[(size_t)n * 64 + mg * 16 + (g << 2)] = r;
    }
  }
  __syncthreads();
  for (int r = 0; r < 2; ++r) {
#pragma unroll
    for (int jj = 0; jj < 2; ++jj) {
      int j = 2 * r + 1 + jj;
      int vt = mg + 8 * r + 4 * jj;
      float4 bv = *(const float4*)(ball + 64 + vt * 16 + (g << 2));
      float ba[4] = {bv.x, bv.y, bv.z, bv.w};
      int lrow0 = (mg + 4 * jj) * 16 + (g << 2);
#pragma unroll
      for (int nt = 0; nt < 3; ++nt) {
        int col = ng * 48 + nt * 16 + arow;
#pragma unroll
        for (int rr = 0; rr < 4; ++rr)
          sO[(lrow0 + rr) * 104 + col] = f2h(acc[j][nt][rr] + ba[rr]);
      }
    }
    __syncthreads();
    for (int idx = tid; idx < 1536; idx += 512) {
      int cc = idx / 12, c4 = idx % 12;
      *(float4*)(vW + ((size_t)(b * 96 + h) * 256 + r * 128 + cc) * 96 + c4 * 8) =
          *(const float4*)&sO[cc * 104 + c4 * 8];
    }
    __syncthreads();
  }
}

// vH[b][w][c][g] = vW[b][g][c][w], both pairs (z selects)
__global__ __launch_bounds__(256) void vtrans(const u16* __restrict__ vW0, const u16* __restrict__ vW1,
                                              u16* __restrict__ vH0, u16* __restrict__ vH1) {
  __shared__ u16 t[96][98];
  const int c = blockIdx.x, b = blockIdx.y;
  const u16* vWp = blockIdx.z ? vW1 : vW0;
  u16* vHp = blockIdx.z ? vH1 : vH0;
  for (int idx = threadIdx.x; idx < 4608; idx += 256) {
    int hh = idx / 48, w2 = idx % 48;
    *(unsigned int*)&t[hh][w2 * 2] =
        *(const unsigned int*)(vWp + (size_t)(b * 96 + hh) * 24576 + c * 96 + w2 * 2);
  }
  __syncthreads();
  for (int idx = threadIdx.x; idx < 4608; idx += 256) {
    int ww = idx / 48, g2 = idx % 48;
    unsigned int lo = t[g2 * 2][ww];
    unsigned int hi = t[g2 * 2 + 1][ww];
    *(unsigned int*)(vHp + (size_t)(b * 96 + ww) * 24576 + c * 96 + g2 * 2) = lo | (hi << 16);
  }
}

// e_h pass (diag-masked), block (p=w, b, pair). Stats -> mH,sH[b][h][w].
// PV output stored TRANSPOSED: tmpHt[b][w][h][c] (256B runs).
__global__ __launch_bounds__(384, 3) void attn1(const u16* __restrict__ Pt0, const u16* __restrict__ Pt1,
                                                const u16* __restrict__ vH0, const u16* __restrict__ vH1,
                                                float* __restrict__ mHs, float* __restrict__ sHs,
                                                u16* __restrict__ tHt0, u16* __restrict__ tHt1) {
  __shared__ __align__(16) char smem[46592];
  u16* vbuf = (u16*)smem;             // [128][104]; transpose overlay [96][136]
  u16* qs = (u16*)smem;               // [96][40]
  u16* ks = (u16*)(smem + 7680);      // [96][40]
  u16* probs = (u16*)(smem + 26624);  // [96][104]
  const int p = blockIdx.x, b = blockIdx.y, pair = blockIdx.z;
  const u16* Qpt = pair ? Pt0 : Pt1;  // pair0: q1,k0,v0 ; pair1: q0,k1,v1
  const u16* Kpt = pair ? Pt1 : Pt0;
  const u16* Vp = pair ? vH1 : vH0;
  u16* tOut = pair ? tHt1 : tHt0;
  float* mOut = mHs + (size_t)pair * (Bn * 9216);
  float* sOut = sHs + (size_t)pair * (Bn * 9216);
  const int tid = threadIdx.x;
  const size_t nbase = (size_t)b * PT_BS;
  const size_t rowoff = (size_t)p * 64;
  const int rstride = 6144;
  for (int idx = tid; idx < 768; idx += 384) {
    int i = idx >> 3, c8 = idx & 7;
    const u16* src = (c8 < 4)
        ? Qpt + nbase + rowoff + (size_t)i * rstride + c8 * 8
        : Kpt + nbase + rowoff + (size_t)i * rstride + 32 + (c8 - 4) * 8;
    float4 v = *(const float4*)src;
    u16* dst = (c8 < 4) ? &qs[i * 40 + c8 * 8] : &ks[i * 40 + (c8 - 4) * 8];
    *(float4*)dst = v;
  }
  __syncthreads();
  const int lane = tid & 63, wv = tid >> 6;
  const int cl = lane & 15, g = lane >> 4;
  const int kc = g * 8;
  const int w0 = wv * 16;
  f32x4 eacc[6];
  {
    f16x8 aq = *(const f16x8*)&qs[(w0 + cl) * 40 + kc];
#pragma unroll
    for (int nt = 0; nt < 6; ++nt) {
      f16x8 bk = *(const f16x8*)&ks[(nt * 16 + cl) * 40 + kc];
      f32x4 zz = {0.f, 0.f, 0.f, 0.f};
      eacc[nt] = __builtin_amdgcn_mfma_f32_16x16x32_f16(aq, bk, zz, 0, 0, 0);
    }
  }
#pragma unroll
  for (int r = 0; r < 4; ++r) {
    int i = w0 + 4 * g + r;
    float m = -1e30f;
#pragma unroll
    for (int nt = 0; nt < 6; ++nt) {
      float e = eacc[nt][r];
      if ((nt * 16 + cl) == i) { e = -1e30f; eacc[nt][r] = e; }
      m = fmaxf(m, e);
    }
    m = fmaxf(m, __shfl_xor(m, 1));
    m = fmaxf(m, __shfl_xor(m, 2));
    m = fmaxf(m, __shfl_xor(m, 4));
    m = fmaxf(m, __shfl_xor(m, 8));
    float s = 0.f;
#pragma unroll
    for (int nt = 0; nt < 6; ++nt) {
      float pv = __expf(eacc[nt][r] - m);
      eacc[nt][r] = pv;
      s += pv;
    }
    s += __shfl_xor(s, 1);
    s += __shfl_xor(s, 2);
    s += __shfl_xor(s, 4);
    s += __shfl_xor(s, 8);
#pragma unroll
    for (int nt = 0; nt < 6; ++nt)
      probs[i * 104 + nt * 16 + cl] = f2h(eacc[nt][r]);
    if (cl == 0) {
      size_t sidx = (size_t)(b * 96 + i) * 96 + p;  // mH[b][h=i][w=p]
      mOut[sidx] = m;
      sOut[sidx] = s;
    }
  }
  __syncthreads();
  f16x8 af[3];
#pragma unroll
  for (int kt = 0; kt < 3; ++kt)
    af[kt] = *(const f16x8*)&probs[(w0 + cl) * 104 + kt * 32 + kc];
  const size_t vbase = (size_t)(b * 96 + p) * 24576;
  for (int half = 0; half < 2; ++half) {
    for (int idx = tid; idx < 1536; idx += 384) {
      int r = idx / 12, c4 = idx % 12;
      *(float4*)&vbuf[r * 104 + c4 * 8] =
          *(const float4*)(Vp + vbase + (size_t)(half * 128 + r) * 96 + c4 * 8);
    }
    __syncthreads();
    f32x4 acc[8];
#pragma unroll
    for (int nt = 0; nt < 8; ++nt) {
      f32x4 a = {0.f, 0.f, 0.f, 0.f};
#pragma unroll
      for (int kt = 0; kt < 3; ++kt) {
        f16x8 bf = *(const f16x8*)&vbuf[(nt * 16 + cl) * 104 + kt * 32 + kc];
        a = __builtin_amdgcn_mfma_f32_16x16x32_f16(af[kt], bf, a, 0, 0, 0);
      }
      acc[nt] = a;
    }
    __syncthreads();
    // transpose: vbuf_t[i=h][c2], pad 136 (16B-aligned rows)
#pragma unroll
    for (int nt = 0; nt < 8; ++nt) {
      int c2 = nt * 16 + cl;
      int wr = w0 + (g << 2);
#pragma unroll
      for (int r = 0; r < 4; ++r) vbuf[(wr + r) * 136 + c2] = f2h(acc[nt][r]);
    }
    __syncthreads();
    // tmpHt[b][w=p][h=i][half*128 + c]: 128 u16 per (i,half) = 16 chunks of 8
    for (int idx = tid; idx < 1536; idx += 384) {
      int i = idx >> 4, c8 = idx & 15;
      *(float4*)(tOut + ((size_t)(b * 96 + p) * 96 + i) * 256 + half * 128 + c8 * 8) =
          *(const float4*)&vbuf[i * 136 + c8 * 8];
    }
    __syncthreads();
  }
}

// Final pass, block (p=h, b, pair): e_w QK^T, local stats + (mH,sH) -> exact
// concat-softmax scales; probs pre-scaled by sclW; PV(vW); outw kept in regs;
// tmpHt slab staged to LDS; out = x + outw + tmpHt*sclH (coalesced fp32 rows).
__global__ __launch_bounds__(384, 3) void pv_comb(const u16* __restrict__ Pt0, const u16* __restrict__ Pt1,
                                                  const u16* __restrict__ vW0, const u16* __restrict__ vW1,
                                                  const float* __restrict__ mHs, const float* __restrict__ sHs,
                                                  const u16* __restrict__ tHt0, const u16* __restrict__ tHt1,
                                                  const float* __restrict__ x0, const float* __restrict__ x1,
                                                  const float* __restrict__ gammaP, float* __restrict__ out) {
  __shared__ __align__(16) char smem[50432];
  u16* vbuf = (u16*)smem;             // [128][104]
  u16* qs = (u16*)smem;               // [96][40]
  u16* ks = (u16*)(smem + 7680);      // [96][40]
  u16* probs = (u16*)(smem + 26624);  // [96][104] ends at 46592
  u16* ttile = (u16*)smem;            // [96][260] = 49920 B, overlays vbuf+probs (both dead)
  float* sclh = (float*)(smem + 49920);  // 96 floats (never overlapped)
  const int p = blockIdx.x, b = blockIdx.y, pair = blockIdx.z;
  const u16* Qpt = pair ? Pt0 : Pt1;
  const u16* Kpt = pair ? Pt1 : Pt0;
  const u16* Vp = pair ? vW1 : vW0;
  const u16* tH = pair ? tHt1 : tHt0;
  const float* x = pair ? x1 : x0;
  const float* mH = mHs + (size_t)pair * (Bn * 9216);
  const float* sH = sHs + (size_t)pair * (Bn * 9216);
  float* o = out + (size_t)pair * Bn * Cn * NHW;
  const int tid = threadIdx.x;
  const size_t nbase = (size_t)b * PT_BS;
  const size_t rowoff = (size_t)p * 6144;
  for (int idx = tid; idx < 768; idx += 384) {
    int i = idx >> 3, c8 = idx & 7;
    const u16* src = (c8 < 4)
        ? Qpt + nbase + rowoff + (size_t)i * 64 + c8 * 8
        : Kpt + nbase + rowoff + (size_t)i * 64 + 32 + (c8 - 4) * 8;
    float4 v = *(const float4*)src;
    u16* dst = (c8 < 4) ? &qs[i * 40 + c8 * 8] : &ks[i * 40 + (c8 - 4) * 8];
    *(float4*)dst = v;
  }
  __syncthreads();
  const int lane = tid & 63, wv = tid >> 6;
  const int cl = lane & 15, g = lane >> 4;
  const int kc = g * 8;
  const int w0 = wv * 16;
  f32x4 eacc[6];
  {
    f16x8 aq = *(const f16x8*)&qs[(w0 + cl) * 40 + kc];
#pragma unroll
    for (int nt = 0; nt < 6; ++nt) {
      f16x8 bk = *(const f16x8*)&ks[(nt * 16 + cl) * 40 + kc];
      f32x4 zz = {0.f, 0.f, 0.f, 0.f};
      eacc[nt] = __builtin_amdgcn_mfma_f32_16x16x32_f16(aq, bk, zz, 0, 0, 0);
    }
  }
  const float gam = gammaP[0];
#pragma unroll
  for (int r = 0; r < 4; ++r) {
    int i = w0 + 4 * g + r;  // i = w index
    float mw = -1e30f;
#pragma unroll
    for (int nt = 0; nt < 6; ++nt) mw = fmaxf(mw, eacc[nt][r]);
    mw = fmaxf(mw, __shfl_xor(mw, 1));
    mw = fmaxf(mw, __shfl_xor(mw, 2));
    mw = fmaxf(mw, __shfl_xor(mw, 4));
    mw = fmaxf(mw, __shfl_xor(mw, 8));
    float sw = 0.f;
#pragma unroll
    for (int nt = 0; nt < 6; ++nt) {
      float pv = __expf(eacc[nt][r] - mw);
      eacc[nt][r] = pv;
      sw += pv;
    }
    sw += __shfl_xor(sw, 1);
    sw += __shfl_xor(sw, 2);
    sw += __shfl_xor(sw, 4);
    sw += __shfl_xor(sw, 8);
    // combine with pass-1 stats: exact concat softmax
    size_t sidx = (size_t)(b * 96 + p) * 96 + i;  // [b][h=p][w=i]
    float mh = mH[sidx], sh = sH[sidx];
    float m = fmaxf(mh, mw);
    float eh_ = __expf(mh - m), ew_ = __expf(mw - m);
    float s = sh * eh_ + sw * ew_;
    float gm = gam / s;
    float sclW = gm * ew_;
#pragma unroll
    for (int nt = 0; nt < 6; ++nt)
      probs[i * 104 + nt * 16 + cl] = f2h(eacc[nt][r] * sclW);
    if (cl == 0) sclh[i] = gm * eh_;
  }
  __syncthreads();
  f16x8 af[3];
#pragma unroll
  for (int kt = 0; kt < 3; ++kt)
    af[kt] = *(const f16x8*)&probs[(w0 + cl) * 104 + kt * 32 + kc];
  const size_t vbase = (size_t)(b * 96 + p) * 24576;
  float4 ro[2][4];
  for (int half = 0; half < 2; ++half) {
    for (int idx = tid; idx < 1536; idx += 384) {
      int r = idx / 12, c4 = idx % 12;
      *(float4*)&vbuf[r * 104 + c4 * 8] =
          *(const float4*)(Vp + vbase + (size_t)(half * 128 + r) * 96 + c4 * 8);
    }
    __syncthreads();
    f32x4 acc[8];
#pragma unroll
    for (int nt = 0; nt < 8; ++nt) {
      f32x4 a = {0.f, 0.f, 0.f, 0.f};
#pragma unroll
      for (int kt = 0; kt < 3; ++kt) {
        f16x8 bf = *(const f16x8*)&vbuf[(nt * 16 + cl) * 104 + kt * 32 + kc];
        a = __builtin_amdgcn_mfma_f32_16x16x32_f16(af[kt], bf, a, 0, 0, 0);
      }
      acc[nt] = a;
    }
    __syncthreads();
#pragma unroll
    for (int nt = 0; nt < 8; ++nt) {
      int c2 = nt * 16 + cl;
      int wr = w0 + (g << 2);
#pragma unroll
      for (int r = 0; r < 4; ++r) vbuf[c2 * 104 + wr + r] = f2h(acc[nt][r]);
    }
    __syncthreads();
    // read back this half's [c][w] rows into registers (4 float4 = 8 u16 each)
#pragma unroll
    for (int k = 0; k < 4; ++k) {
      int idx = tid + k * 384;
      int cc = idx / 12, c4 = idx % 12;
      ro[half][k] = *(const float4*)&vbuf[cc * 104 + c4 * 8];
    }
    __syncthreads();
  }
  // stage tmpHt slab for (b, h=p): ttile[w][c], 256 u16 per row = 32 chunks of 8
  for (int idx = tid; idx < 3072; idx += 384) {
    int w = idx >> 5, c16 = idx & 31;
    *(float4*)&ttile[w * 260 + c16 * 8] =
        *(const float4*)(tH + ((size_t)(b * 96 + w) * 96 + p) * 256 + c16 * 8);
  }
  __syncthreads();
  // combine: out[b][C][p][w] = x + outw + ttile[w][C]*sclh[w]
#pragma unroll
  for (int half = 0; half < 2; ++half) {
#pragma unroll
    for (int k = 0; k < 4; ++k) {
      int idx = tid + k * 384;
      int cc = idx / 12, c4 = idx % 12;
      int C = half * 128 + cc;
      size_t go = ((size_t)(b * 256 + C) * 96 + p) * 96 + c4 * 8;
      float4 xv0 = *(const float4*)(x + go);
      float4 xv1 = *(const float4*)(x + go + 4);
      const u16* rw = (const u16*)&ro[half][k];
      float r0[8];
#pragma unroll
      for (int j = 0; j < 8; ++j) {
        int wj = c4 * 8 + j;
        r0[j] = h2f(rw[j]) + h2f(ttile[wj * 260 + C]) * sclh[wj];
      }
      float4 ov0 = make_float4(xv0.x + r0[0], xv0.y + r0[1], xv0.z + r0[2], xv0.w + r0[3]);
      float4 ov1 = make_float4(xv1.x + r0[4], xv1.y + r0[5], xv1.z + r0[6], xv1.w + r0[7]);
      *(float4*)(o + go) = ov0;
      *(float4*)(o + go + 4) = ov1;
    }
  }
}

extern "C" void kernel_launch(void* const* d_in, const int* in_sizes, int n_in,
                              void* d_out, int out_size, void* d_ws, size_t ws_size,
                              hipStream_t stream) {
  const float* x0 = (const float*)d_in[0];
  const float* x1 = (const float*)d_in[1];
  const float* wq0 = (const float*)d_in[2];
  const float* bq0 = (const float*)d_in[3];
  const float* wk0 = (const float*)d_in[4];
  const float* bk0 = (const float*)d_in[5];
  const float* wv0 = (const float*)d_in[6];
  const float* bv0 = (const float*)d_in[7];
  const float* wq1 = (const float*)d_in[8];
  const float* bq1 = (const float*)d_in[9];
  const float* wk1 = (const float*)d_in[10];
  const float* bk1 = (const float*)d_in[11];
  const float* wv1 = (const float*)d_in[12];
  const float* bv1 = (const float*)d_in[13];
  const float* gamma = (const float*)d_in[14];
  float* out = (float*)d_out;

  char* ws = (char*)d_ws;
  size_t off = 0;
  auto alloc = [&](size_t bytes) -> void* {
    void* ptr = ws + off;
    off += (bytes + 255) & ~(size_t)255;
    return ptr;
  };
  const size_t SZ_P = (size_t)Bn * NHW * 64 * 2;   // 9.4 MB (f16)
  const size_t SZ_V = (size_t)Bn * NHW * Cn * 2;   // 37.7 MB
  const size_t SZ_S = (size_t)Bn * 9216 * 4;       // 294 KB
  u16* Pt0 = (u16*)alloc(SZ_P);
  u16* Pt1 = (u16*)alloc(SZ_P);
  u16* vW0 = (u16*)alloc(SZ_V);
  u16* vW1 = (u16*)alloc(SZ_V);
  u16* vH0 = (u16*)alloc(SZ_V);
  u16* vH1 = (u16*)alloc(SZ_V);
  u16* tHt0 = (u16*)alloc(SZ_V);
  u16* tHt1 = (u16*)alloc(SZ_V);
  u16* Wall0 = (u16*)alloc(320 * 256 * 2);
  u16* Wall1 = (u16*)alloc(320 * 256 * 2);
  float* ball0 = (float*)alloc(320 * 4);
  float* ball1 = (float*)alloc(320 * 4);
  float* mH = (float*)alloc(2 * SZ_S);
  float* sH = (float*)alloc(2 * SZ_S);
  (void)ws_size; (void)in_sizes; (void)n_in; (void)out_size;

  dim3 gpk(320, 2), gp(96, Bn, 2), gt(256, Bn, 2), ga(96, Bn, 2);
  pack_all<<<gpk, 256, 0, stream>>>(wq0, bq0, wk0, bk0, wv0, bv0,
                                    wq1, bq1, wk1, bk1, wv1, bv1,
                                    Wall0, ball0, Wall1, ball1);
  proj_all<<<gp, 512, 0, stream>>>(x0, x1, Wall0, Wall1, ball0, ball1, Pt0, Pt1, vW0, vW1);
  vtrans<<<gt, 256, 0, stream>>>(vW0, vW1, vH0, vH1);
  attn1<<<ga, 384, 0, stream>>>(Pt0, Pt1, vH0, vH1, mH, sH, tHt0, tHt1);
  pv_comb<<<ga, 384, 0, stream>>>(Pt0, Pt1, vW0, vW1, mH, sH, tHt0, tHt1, x0, x1, gamma, out);
}